// Round 18
// baseline (161.020 us; speedup 1.0000x reference)
//
#include <hip/hip_runtime.h>
#include <hip/hip_bf16.h>
#include <stdint.h>

typedef __attribute__((ext_vector_type(8))) __bf16 bf16x8;
typedef __attribute__((ext_vector_type(4))) float f32x4;

#define MFMA __builtin_amdgcn_mfma_f32_16x16x32_bf16

// fp32 -> bf16 round-to-nearest-even (scalar)
__device__ __forceinline__ uint16_t f2bf(float f) {
  uint32_t u = __float_as_uint(f);
  return (uint16_t)((u + 0x7fffu + ((u >> 16) & 1u)) >> 16);
}

// paired fp32x2 -> bf16x2 via intrinsic (compiler emits v_cvt_pk_bf16_f32)
__device__ __forceinline__ uint32_t pkcvt(float lo, float hi) {
  union { __hip_bfloat162 b; uint32_t u; } cv;
  cv.b = __float22bfloat162_rn(float2{lo, hi});
  return cv.u;
}

// fast tanh, clamp-free: 1 - 2/(1+e^{2x}); IEEE-exact at +-inf; 5 VALU ops
__device__ __forceinline__ float ftanh(float v) {
  float e = __builtin_amdgcn_exp2f(v * 2.885390081777927f);
  return 1.f - 2.f * __builtin_amdgcn_rcpf(e + 1.f);
}

// async 16B global->LDS (zero staging VGPRs)
__device__ __forceinline__ void gl2lds16(const void* g, void* l) {
  __builtin_amdgcn_global_load_lds(
      (const __attribute__((address_space(1))) unsigned int*)g,
      (__attribute__((address_space(3))) unsigned int*)l, 16, 0, 0);
}

// A-tile LDS addr: row-major [rows][512B], 16B chunks XOR (row&7) (T2).
// Staging writes LINEAR; the XOR is applied to the per-lane global SOURCE.
__device__ __forceinline__ int lds_addr(int row, int chunk) {
  return row * 512 + ((chunk ^ (row & 7)) << 4);
}

// 16-cols-per-wave GEMM: NRF*16 out rows x 16 cols; bfrag (32 VGPR) resident.
template<int NRF>
__device__ __forceinline__ void gemmN(const uint8_t* base, const bf16x8 bfrag[8],
                                      int l15, int l4, f32x4 acc[NRF]) {
  __builtin_amdgcn_s_setprio(1);
#pragma unroll
  for (int s = 0; s < 8; ++s) {
#pragma unroll
    for (int rf = 0; rf < NRF; ++rf) {
      bf16x8 a = *reinterpret_cast<const bf16x8*>(&base[lds_addr(rf * 16 + l15, s * 4 + l4)]);
      acc[rf] = MFMA(a, bfrag[s], acc[rf], 0, 0, 0);
    }
  }
  __builtin_amdgcn_s_setprio(0);
}

__device__ __forceinline__ void load_bfrag8(const uint16_t* __restrict__ Wbf,
                                            int col, int l4, bf16x8 bfrag[8]) {
#pragma unroll
  for (int s = 0; s < 8; ++s)
    bfrag[s] = *reinterpret_cast<const bf16x8*>(Wbf + col * 256 + s * 32 + l4 * 8);
}

// stage one 32-row (16KB) A-tile: 1024 chunks, 2 per thread, pre-swizzled source
template<bool LEAF>
__device__ __forceinline__ void stage_tile(
    uint8_t* dst, const uint16_t* __restrict__ X,
    const int* __restrict__ pos_idx, const int* __restrict__ wrd_idx,
    const uint16_t* __restrict__ pos_bf, const uint16_t* __restrict__ wrd_bf,
    int rowbase, int tid)
{
#pragma unroll
  for (int k = 0; k < 2; ++k) {
    const int ct = tid + k * 512;            // linear chunk [0,1024)
    const int arow = ct >> 5;                // A-row [0,32)
    const int c = (ct & 31) ^ (arow & 7);    // pre-swizzled logical chunk
    const void* src;
    if (LEAF) {
      const int seg = c >> 3;                // [posL|wrdL|posR|wrdR]
      const int leaf = 2 * (rowbase + arow) + (seg >> 1);
      const int idx = (seg & 1) ? wrd_idx[leaf] : pos_idx[leaf];
      const uint16_t* tab = (seg & 1) ? wrd_bf : pos_bf;
      src = tab + (size_t)idx * 64 + (c & 7) * 8;
    } else {
      src = X + ((size_t)(rowbase + arow)) * 256 + c * 8;
    }
    gl2lds16(src, &dst[ct << 4]);
  }
}

// ---- fused 3/4-level kernel, 48 KiB LDS ----
// L1 double-buffered: four 32-row tiles ping-pong two 16KB halves of [0,32K);
// stage(t+1) issued BEFORE gemm(t) so gather latency hides under MFMA+epilogue.
// Regions: A/Mid1 [0,32K); Mid2 [32K,48K); FOUR=false: OutS [0,8K);
//          FOUR=true:  Mid3 [0,8K), OutS4 [32K,36K).
template<bool LEAF, bool FOUR>
__global__ __launch_bounds__(512, 4)
void fused_kernel(const uint16_t* __restrict__ X,
                  const int* __restrict__ pos_idx, const int* __restrict__ wrd_idx,
                  const uint16_t* __restrict__ pos_bf, const uint16_t* __restrict__ wrd_bf,
                  uint16_t* __restrict__ Y, const uint16_t* __restrict__ Wbf,
                  const float* __restrict__ wnp,
                  const int* __restrict__ nidx, int off1, int off2, int off3, int off4)
{
  __shared__ uint8_t Abuf[49152];
  const int tid = threadIdx.x, wv = tid >> 6, lane = tid & 63;
  const int l15 = lane & 15, l4 = lane >> 4;
  const int col = wv * 16 + l15;
  const int b0 = blockIdx.x;

  bf16x8 bfrag[8];
  load_bfrag8(Wbf, col, l4, bfrag);

  uint32_t pk1[4][4];

  // ---- L1: four 32-row tiles, double-buffered ----
  stage_tile<LEAF>(Abuf, X, pos_idx, wrd_idx, pos_bf, wrd_bf, b0 * 128, tid);
  __syncthreads();                           // tile 0 staged
#pragma unroll
  for (int t = 0; t < 4; ++t) {
    if (t < 3)
      stage_tile<LEAF>(Abuf + (((t + 1) & 1) << 14), X, pos_idx, wrd_idx,
                       pos_bf, wrd_bf, b0 * 128 + (t + 1) * 32, tid);
    f32x4 acc[2] = {};
    gemmN<2>(Abuf + ((t & 1) << 14), bfrag, l15, l4, acc);
#pragma unroll
    for (int rf = 0; rf < 2; ++rf)
#pragma unroll
      for (int p = 0; p < 2; ++p) {
        const int r1 = t * 32 + rf * 16 + l4 * 4 + 2 * p;
        const int2 ni = *reinterpret_cast<const int2*>(nidx + off1 + b0 * 128 + r1);
        pk1[t][rf * 2 + p] = pkcvt(ftanh(acc[rf][2 * p]     + wnp[ni.x * 128 + col]),
                                   ftanh(acc[rf][2 * p + 1] + wnp[ni.y * 128 + col]));
      }
    __syncthreads();                         // tile t reads done + tile t+1 staged
  }

  // ---- Mid1 write (128 L1 rows -> 64 A-rows, overlays Abuf[0:32K)) ----
#pragma unroll
  for (int t = 0; t < 4; ++t)
#pragma unroll
    for (int rf = 0; rf < 2; ++rf)
#pragma unroll
      for (int reg = 0; reg < 4; ++reg) {
        const int r1 = t * 32 + rf * 16 + l4 * 4 + reg;
        const int r2 = r1 >> 1;
        const int colA = (r1 & 1) * 128 + col;
        const uint16_t vv = (uint16_t)(pk1[t][rf * 2 + (reg >> 1)] >> ((reg & 1) * 16));
        *reinterpret_cast<uint16_t*>(
            &Abuf[r2 * 512 + (((colA >> 3) ^ (r2 & 7)) << 4) + (colA & 7) * 2]) = vv;
      }
  __syncthreads();                           // Mid1 complete

  // ---- L2: gemm from Mid1; epilogue writes Mid2 [32K,48K) directly ----
  {
    f32x4 acc[4] = {};
    gemmN<4>(Abuf, bfrag, l15, l4, acc);
    uint8_t* Mid2 = Abuf + 32768;
#pragma unroll
    for (int rf = 0; rf < 4; ++rf)
#pragma unroll
      for (int reg = 0; reg < 4; ++reg) {
        const int r2 = rf * 16 + l4 * 4 + reg;          // L2 row [0,64)
        const int ni = nidx[off2 + b0 * 64 + r2];
        const float v = acc[rf][reg] + wnp[ni * 128 + col];
        const int r3 = r2 >> 1;
        const int colA = (r2 & 1) * 128 + col;
        *reinterpret_cast<uint16_t*>(
            &Mid2[r3 * 512 + (((colA >> 3) ^ (r3 & 7)) << 4) + (colA & 7) * 2]) =
            f2bf(ftanh(v));
      }
  }
  __syncthreads();                           // Mid2 complete (+ Mid1 reads done)

  // ---- L3: gemm from Mid2 (32 rows) ----
  {
    f32x4 acc[2] = {};
    gemmN<2>(Abuf + 32768, bfrag, l15, l4, acc);
#pragma unroll
    for (int rf = 0; rf < 2; ++rf)
#pragma unroll
      for (int reg = 0; reg < 4; ++reg) {
        const int row = rf * 16 + l4 * 4 + reg;         // L3 row [0,32)
        const int ni = nidx[off3 + b0 * 32 + row];
        const float v = acc[rf][reg] + wnp[ni * 128 + col];
        if (FOUR) {
          const int r4 = row >> 1;                      // Mid3 A-format [0,8K)
          const int colA = (row & 1) * 128 + col;
          *reinterpret_cast<uint16_t*>(
              &Abuf[r4 * 512 + (((colA >> 3) ^ (r4 & 7)) << 4) + (colA & 7) * 2]) =
              f2bf(ftanh(v));
        } else {
          const int colb = col * 2;                     // OutS natural [0,8K)
          *reinterpret_cast<uint16_t*>(
              &Abuf[row * 256 + (((colb >> 4) ^ (row & 7)) << 4) + (colb & 15)]) =
              f2bf(ftanh(v));
        }
      }
  }
  __syncthreads();                           // Mid3/OutS complete (+ Mid2 reads done)

  if (FOUR) {
    // ---- L4: gemm from Mid3 [0,8K) (16 A-rows); OutS4 -> [32K,36K) ----
    f32x4 acc[1] = {};
    gemmN<1>(Abuf, bfrag, l15, l4, acc);
    uint8_t* OutS4 = Abuf + 32768;
#pragma unroll
    for (int reg = 0; reg < 4; ++reg) {
      const int row = l4 * 4 + reg;                     // L4 row [0,16)
      const int ni = nidx[off4 + b0 * 16 + row];
      const float v = acc[0][reg] + wnp[ni * 128 + col];
      const int colb = col * 2;
      *reinterpret_cast<uint16_t*>(
          &OutS4[row * 256 + (((colb >> 4) ^ (row & 7)) << 4) + (colb & 15)]) =
          f2bf(ftanh(v));
    }
    __syncthreads();
    if (tid < 256) {                         // 16 rows x 256B = 4KB out
      const int i = tid >> 4, c = tid & 15;
      int4 v = *reinterpret_cast<const int4*>(&OutS4[i * 256 + ((c ^ (i & 7)) << 4)]);
      *reinterpret_cast<int4*>(
          reinterpret_cast<uint8_t*>(Y) + ((size_t)b0 * 16 + i) * 256 + c * 16) = v;
    }
  } else {
    const int i = tid >> 4, c = tid & 15;    // 32 rows x 256B = 8KB out
    int4 v = *reinterpret_cast<const int4*>(&Abuf[i * 256 + ((c ^ (i & 7)) << 4)]);
    *reinterpret_cast<int4*>(
        reinterpret_cast<uint8_t*>(Y) + ((size_t)b0 * 32 + i) * 256 + c * 16) = v;
  }
}

// ---- tail: levels n=256..1 in ONE block (round-17 version) ----
__global__ __launch_bounds__(512, 1)
void tail_kernel(const uint16_t* __restrict__ X, const uint16_t* __restrict__ Wbf,
                 const float* __restrict__ wnp,
                 const int* __restrict__ nidx, int base_off, float* __restrict__ out)
{
  __shared__ uint8_t P[98304];   // ping-pong: A @0 (<=64KB) / @65536 (<=32KB)
  const int tid = threadIdx.x, wv = tid >> 6, lane = tid & 63;
  const int l15 = lane & 15, l4 = lane >> 4;
  const int col = wv * 16 + l15;

  bf16x8 bfrag[8];
  load_bfrag8(Wbf, col, l4, bfrag);

  int off = base_off;

  // n=256: A (256 A-rows) from global; Mid (128 A-rows, 64KB) -> P[0]
  for (int t = 0; t < 4; ++t) {
    f32x4 acc[4] = {};
#pragma unroll
    for (int s = 0; s < 8; ++s)
#pragma unroll
      for (int rf = 0; rf < 4; ++rf) {
        bf16x8 a = *reinterpret_cast<const bf16x8*>(
            X + (size_t)(t * 64 + rf * 16 + l15) * 256 + s * 32 + l4 * 8);
        acc[rf] = MFMA(a, bfrag[s], acc[rf], 0, 0, 0);
      }
#pragma unroll
    for (int rf = 0; rf < 4; ++rf)
#pragma unroll
      for (int reg = 0; reg < 4; ++reg) {
        const int r1 = t * 64 + rf * 16 + l4 * 4 + reg;   // [0,256)
        const int ni = nidx[off + r1];
        const float v = acc[rf][reg] + wnp[ni * 128 + col];
        const int r2 = r1 >> 1;
        const int colA = (r1 & 1) * 128 + col;
        *reinterpret_cast<uint16_t*>(
            &P[r2 * 512 + (((colA >> 3) ^ (r2 & 7)) << 4) + (colA & 7) * 2]) =
            f2bf(ftanh(v));
      }
  }
  off += 256;
  __syncthreads();

  int cur = 0;                               // A for n=128 at P[0]
  for (int n = 128; n >= 1; n >>= 1) {
    const uint8_t* Pin = P + (cur ? 65536 : 0);
    uint8_t* Pout = P + (cur ? 0 : 65536);
    const int ntiles = (n + 63) >> 6;
    for (int t = 0; t < ntiles; ++t) {
      f32x4 acc[4] = {};
      gemmN<4>(Pin + t * 32768, bfrag, l15, l4, acc);
#pragma unroll
      for (int rf = 0; rf < 4; ++rf)
#pragma unroll
        for (int reg = 0; reg < 4; ++reg) {
          const int r1 = t * 64 + rf * 16 + l4 * 4 + reg;
          const int rcl = r1 < n ? r1 : n - 1;           // clamp for garbage rows
          const int ni = nidx[off + rcl];
          const float v = acc[rf][reg] + wnp[ni * 128 + col];
          const float y = ftanh(v);
          if (n == 1) {
            if (r1 == 0) out[col] = y;
          } else if (r1 < n) {
            const int r2 = r1 >> 1;
            const int colA = (r1 & 1) * 128 + col;
            *reinterpret_cast<uint16_t*>(
                &Pout[r2 * 512 + (((colA >> 3) ^ (r2 & 7)) << 4) + (colA & 7) * 2]) =
                f2bf(y);
          }
        }
    }
    off += n;
    cur ^= 1;
    __syncthreads();
  }
}

// ---- prep: Wc_w/Wpos/Wwrd fp32->bf16; wnp = Wnon + bias (fp32) ----
__global__ void prep_all(const float* __restrict__ Wc_w, const float* __restrict__ Wpos,
                         const float* __restrict__ Wwrd, const float* __restrict__ Wnon,
                         const float* __restrict__ bias,
                         uint16_t* __restrict__ wc_bf, uint16_t* __restrict__ pos_bf,
                         uint16_t* __restrict__ wrd_bf, float* __restrict__ wnp)
{
  int g = blockIdx.x * 256 + threadIdx.x;
  if (g >= 804608) {                          // Wnon + bias -> fp32
    const int idx = g - 804608;               // [0,1024)
    float4 f0 = reinterpret_cast<const float4*>(Wnon)[idx * 2];
    float4 f1 = reinterpret_cast<const float4*>(Wnon)[idx * 2 + 1];
    const int cb = (idx * 8) & 127;
    f0.x += bias[cb];     f0.y += bias[cb + 1]; f0.z += bias[cb + 2]; f0.w += bias[cb + 3];
    f1.x += bias[cb + 4]; f1.y += bias[cb + 5]; f1.z += bias[cb + 6]; f1.w += bias[cb + 7];
    reinterpret_cast<float4*>(wnp)[idx * 2] = f0;
    reinterpret_cast<float4*>(wnp)[idx * 2 + 1] = f1;
    return;
  }
  const float* src; uint16_t* dst; int idx;
  if (g < 4096)      { src = Wc_w; dst = wc_bf;  idx = g; }
  else if (g < 4608) { src = Wpos; dst = pos_bf; idx = g - 4096; }
  else               { src = Wwrd; dst = wrd_bf; idx = g - 4608; }
  float4 f0 = reinterpret_cast<const float4*>(src)[idx * 2];
  float4 f1 = reinterpret_cast<const float4*>(src)[idx * 2 + 1];
  union { int4 v; uint16_t u[8]; } pkv;
  pkv.u[0] = f2bf(f0.x); pkv.u[1] = f2bf(f0.y); pkv.u[2] = f2bf(f0.z); pkv.u[3] = f2bf(f0.w);
  pkv.u[4] = f2bf(f1.x); pkv.u[5] = f2bf(f1.y); pkv.u[6] = f2bf(f1.z); pkv.u[7] = f2bf(f1.w);
  reinterpret_cast<int4*>(dst)[idx] = pkv.v;
}

extern "C" void kernel_launch(void* const* d_in, const int* in_sizes, int n_in,
                              void* d_out, int out_size, void* d_ws, size_t ws_size,
                              hipStream_t stream)
{
  const int*   pos_idx = (const int*)d_in[0];
  const int*   wrd_idx = (const int*)d_in[1];
  const int*   non_idx = (const int*)d_in[2];
  const float* Wwrd    = (const float*)d_in[3];
  const float* Wpos    = (const float*)d_in[4];
  const float* Wnon    = (const float*)d_in[5];
  const float* Wc_w    = (const float*)d_in[6];
  const float* Wc_b    = (const float*)d_in[7];
  float* out = (float*)d_out;

  uint8_t* ws = (uint8_t*)d_ws;
  uint16_t* Wbf    = (uint16_t*)ws;                    // 64 KiB
  uint16_t* pos_bf = (uint16_t*)(ws + 65536);          // 8 KiB
  float*    wnp    = (float*)(ws + 73728);             // 32 KiB (Wnon+bias)
  uint16_t* wrd_bf = (uint16_t*)(ws + 106496);         // 12.8 MB
  uint16_t* S1     = (uint16_t*)(ws + 12906496);       // 16.8 MB (65536x128)
  uint16_t* S2     = (uint16_t*)(ws + 29683712);       // 2.1 MB  (8192x128)
  uint16_t* S4     = (uint16_t*)(ws + 31780864);       // 128 KB  (512x128)

  prep_all<<<3147, 256, 0, stream>>>(Wc_w, Wpos, Wwrd, Wnon, Wc_b,
                                     Wbf, pos_bf, wrd_bf, wnp);

  // Level offsets into non_idx: L1=0(262144), L2=262144(131072), L3=393216(65536),
  // L4=458752(32768), L5=491520(16384), L6=507904(8192), L7=516096(4096),
  // L8=520192(2048), L9=522240(1024), L10=523264(512), tail from 523776(256..1).

  // K1: gather -> L1,L2,L3 -> S1 (65536 rows)
  fused_kernel<true, false><<<2048, 512, 0, stream>>>(
      nullptr, pos_idx, wrd_idx, pos_bf, wrd_bf, S1, Wbf, wnp, non_idx,
      0, 262144, 393216, 0);
  // K2: S1 -> L4,L5,L6 -> S2 (8192 rows)
  fused_kernel<false, false><<<256, 512, 0, stream>>>(
      S1, nullptr, nullptr, nullptr, nullptr, S2, Wbf, wnp, non_idx,
      458752, 491520, 507904, 0);
  // K3: S2 -> L7,L8,L9,L10 -> S4 (512 rows)
  fused_kernel<false, true><<<32, 512, 0, stream>>>(
      S2, nullptr, nullptr, nullptr, nullptr, S4, Wbf, wnp, non_idx,
      516096, 520192, 522240, 523264);
  // tail: 256..1 (reads 512 rows in S4)
  tail_kernel<<<1, 512, 0, stream>>>(S4, Wbf, wnp, non_idx, 523776, out);
}

// Round 19
// 156.069 us; speedup vs baseline: 1.0317x; 1.0317x over previous
//
#include <hip/hip_runtime.h>
#include <hip/hip_bf16.h>
#include <stdint.h>

typedef __attribute__((ext_vector_type(8))) __bf16 bf16x8;
typedef __attribute__((ext_vector_type(4))) float f32x4;

#define MFMA __builtin_amdgcn_mfma_f32_16x16x32_bf16

// fp32 -> bf16 round-to-nearest-even (prep only)
__device__ __forceinline__ uint16_t f2bf(float f) {
  uint32_t u = __float_as_uint(f);
  return (uint16_t)((u + 0x7fffu + ((u >> 16) & 1u)) >> 16);
}

// paired fp32x2 -> bf16x2 via intrinsic (compiler emits v_cvt_pk_bf16_f32)
__device__ __forceinline__ uint32_t pkcvt(float lo, float hi) {
  union { __hip_bfloat162 b; uint32_t u; } cv;
  cv.b = __float22bfloat162_rn(float2{lo, hi});
  return cv.u;
}

// fast tanh, clamp-free: 1 - 2/(1+e^{2x}); IEEE-exact at +-inf; 5 VALU ops
__device__ __forceinline__ float ftanh(float v) {
  float e = __builtin_amdgcn_exp2f(v * 2.885390081777927f);
  return 1.f - 2.f * __builtin_amdgcn_rcpf(e + 1.f);
}

// async 16B global->LDS (zero staging VGPRs)
__device__ __forceinline__ void gl2lds16(const void* g, void* l) {
  __builtin_amdgcn_global_load_lds(
      (const __attribute__((address_space(1))) unsigned int*)g,
      (__attribute__((address_space(3))) unsigned int*)l, 16, 0, 0);
}

// A-tile LDS addr: row-major [rows][512B], 16B chunks XOR (row&7) (T2).
// Staging writes LINEAR; the XOR is applied to the per-lane global SOURCE.
__device__ __forceinline__ int lds_addr(int row, int chunk) {
  return row * 512 + ((chunk ^ (row & 7)) << 4);
}
// u32 store addr for interleaved pair (k'=2col, 2col+1) in A-row r2
__device__ __forceinline__ int ildw_addr(int r2, int col) {
  return r2 * 512 + (((col >> 2) ^ (r2 & 7)) << 4) + ((col & 3) << 2);
}

// 16-cols-per-wave GEMM: NRF*16 out rows x 16 cols; bfrag (32 VGPR) resident.
template<int NRF>
__device__ __forceinline__ void gemmN(const uint8_t* base, const bf16x8 bfrag[8],
                                      int l15, int l4, f32x4 acc[NRF]) {
  __builtin_amdgcn_s_setprio(1);
#pragma unroll
  for (int s = 0; s < 8; ++s) {
#pragma unroll
    for (int rf = 0; rf < NRF; ++rf) {
      bf16x8 a = *reinterpret_cast<const bf16x8*>(&base[lds_addr(rf * 16 + l15, s * 4 + l4)]);
      acc[rf] = MFMA(a, bfrag[s], acc[rf], 0, 0, 0);
    }
  }
  __builtin_amdgcn_s_setprio(0);
}

__device__ __forceinline__ void load_bfrag8(const uint16_t* __restrict__ Wb,
                                            int col, int l4, bf16x8 bfrag[8]) {
#pragma unroll
  for (int s = 0; s < 8; ++s)
    bfrag[s] = *reinterpret_cast<const bf16x8*>(Wb + col * 256 + s * 32 + l4 * 8);
}

// ---- fused 3/4-level kernel, 48 KiB LDS, INTERLEAVED state (k'=2col+side) ----
// Global state = A-format: A-row r2 holds rows [2r2, 2r2+1], unswizzled.
// Leaf L1 uses natural-order WbfN; all other levels use interleaved WbfI.
// Regions: A/Mid1 [0,32K); Mid2 [32K,48K); FOUR=false: OutS [0,8K);
//          FOUR=true:  Mid3 [0,8K), OutS4 [32K,36K).
template<bool LEAF, bool FOUR>
__global__ __launch_bounds__(512, 4)
void fused_kernel(const uint16_t* __restrict__ X,
                  const int* __restrict__ pos_idx, const int* __restrict__ wrd_idx,
                  const uint16_t* __restrict__ pos_bf, const uint16_t* __restrict__ wrd_bf,
                  uint16_t* __restrict__ Y,
                  const uint16_t* __restrict__ WbfN, const uint16_t* __restrict__ WbfI,
                  const float* __restrict__ wnp,
                  const int* __restrict__ nidx, int off1, int off2, int off3, int off4)
{
  __shared__ uint8_t Abuf[49152];
  const int tid = threadIdx.x, wv = tid >> 6, lane = tid & 63;
  const int l15 = lane & 15, l4 = lane >> 4;
  const int col = wv * 16 + l15;
  const int b0 = blockIdx.x;

  bf16x8 bfrag[8];
  load_bfrag8(LEAF ? WbfN : WbfI, col, l4, bfrag);

  uint32_t pk1[2][8];

  // ---- L1: two 64-row tiles through Abuf[0:32K) (round-17 tiling) ----
#pragma unroll
  for (int t = 0; t < 2; ++t) {
#pragma unroll
    for (int k = 0; k < 4; ++k) {
      const int ct = tid + k * 512;          // linear LDS chunk [0,2048)
      const int arow = ct >> 5;
      const int c = (ct & 31) ^ (arow & 7);  // pre-swizzled logical chunk
      const void* src;
      if (LEAF) {
        const int seg = c >> 3;              // [posL|wrdL|posR|wrdR]
        const int leaf = 2 * (b0 * 128 + t * 64 + arow) + (seg >> 1);
        const int idx = (seg & 1) ? wrd_idx[leaf] : pos_idx[leaf];
        const uint16_t* tab = (seg & 1) ? wrd_bf : pos_bf;
        src = tab + (size_t)idx * 64 + (c & 7) * 8;
      } else {
        src = X + ((size_t)(b0 * 128 + t * 64 + arow)) * 256 + c * 8;
      }
      gl2lds16(src, &Abuf[ct << 4]);
    }
    __syncthreads();                         // staged

    f32x4 acc[4] = {};
    gemmN<4>(Abuf, bfrag, l15, l4, acc);
#pragma unroll
    for (int rf = 0; rf < 4; ++rf)
#pragma unroll
      for (int p = 0; p < 2; ++p) {
        const int r1 = t * 64 + rf * 16 + l4 * 4 + 2 * p;
        const int2 ni = *reinterpret_cast<const int2*>(nidx + off1 + b0 * 128 + r1);
        pk1[t][rf * 2 + p] = pkcvt(ftanh(acc[rf][2 * p]     + wnp[ni.x * 128 + col]),
                                   ftanh(acc[rf][2 * p + 1] + wnp[ni.y * 128 + col]));
      }
    __syncthreads();                         // tile t LDS reads done
  }

  if (LEAF) load_bfrag8(WbfI, col, l4, bfrag);   // interleaved B for L2+

  // ---- Mid1 write: 16 u32 pair-stores -> [0,32K) ----
#pragma unroll
  for (int t = 0; t < 2; ++t)
#pragma unroll
    for (int rf = 0; rf < 4; ++rf)
#pragma unroll
      for (int p = 0; p < 2; ++p) {
        const int r2 = t * 32 + rf * 8 + l4 * 2 + p;
        *reinterpret_cast<uint32_t*>(&Abuf[ildw_addr(r2, col)]) = pk1[t][rf * 2 + p];
      }
  __syncthreads();                           // Mid1 complete

  // ---- L2: gemm from Mid1; pair epilogue -> Mid2 [32K,48K) direct ----
  {
    f32x4 acc[4] = {};
    gemmN<4>(Abuf, bfrag, l15, l4, acc);
    uint8_t* Mid2 = Abuf + 32768;
#pragma unroll
    for (int rf = 0; rf < 4; ++rf)
#pragma unroll
      for (int p = 0; p < 2; ++p) {
        const int r2 = rf * 16 + l4 * 4 + 2 * p;        // L2 row [0,64)
        const int2 ni = *reinterpret_cast<const int2*>(nidx + off2 + b0 * 64 + r2);
        *reinterpret_cast<uint32_t*>(&Mid2[ildw_addr(r2 >> 1, col)]) =
            pkcvt(ftanh(acc[rf][2 * p]     + wnp[ni.x * 128 + col]),
                  ftanh(acc[rf][2 * p + 1] + wnp[ni.y * 128 + col]));
      }
  }
  __syncthreads();                           // Mid2 complete (+ Mid1 reads done)

  // ---- L3: gemm from Mid2 (32 rows); pair epilogue -> [0,8K) direct ----
  {
    f32x4 acc[2] = {};
    gemmN<2>(Abuf + 32768, bfrag, l15, l4, acc);
#pragma unroll
    for (int rf = 0; rf < 2; ++rf)
#pragma unroll
      for (int p = 0; p < 2; ++p) {
        const int r3 = rf * 16 + l4 * 4 + 2 * p;        // L3 row [0,32)
        const int2 ni = *reinterpret_cast<const int2*>(nidx + off3 + b0 * 32 + r3);
        *reinterpret_cast<uint32_t*>(&Abuf[ildw_addr(r3 >> 1, col)]) =
            pkcvt(ftanh(acc[rf][2 * p]     + wnp[ni.x * 128 + col]),
                  ftanh(acc[rf][2 * p + 1] + wnp[ni.y * 128 + col]));
      }
  }
  __syncthreads();                           // L3out complete (+ Mid2 reads done)

  if (FOUR) {
    // ---- L4: gemm from [0,8K) (16 A-rows); pair epilogue -> [32K,36K) ----
    f32x4 acc[1] = {};
    gemmN<1>(Abuf, bfrag, l15, l4, acc);
    uint8_t* O4 = Abuf + 32768;
#pragma unroll
    for (int p = 0; p < 2; ++p) {
      const int r4 = l4 * 4 + 2 * p;                    // L4 row [0,16)
      const int2 ni = *reinterpret_cast<const int2*>(nidx + off4 + b0 * 16 + r4);
      *reinterpret_cast<uint32_t*>(&O4[ildw_addr(r4 >> 1, col)]) =
          pkcvt(ftanh(acc[0][2 * p]     + wnp[ni.x * 128 + col]),
                ftanh(acc[0][2 * p + 1] + wnp[ni.y * 128 + col]));
    }
    __syncthreads();
    if (tid < 256) {                         // 8 A-rows x 512B = 4KB out (de-swizzle)
      const int i = tid >> 5, c = tid & 31;
      int4 v = *reinterpret_cast<const int4*>(&O4[i * 512 + ((c ^ (i & 7)) << 4)]);
      *reinterpret_cast<int4*>(
          reinterpret_cast<uint8_t*>(Y) + (size_t)b0 * 4096 + i * 512 + c * 16) = v;
    }
  } else {
    const int i = tid >> 5, c = tid & 31;    // 16 A-rows x 512B = 8KB out (de-swizzle)
    int4 v = *reinterpret_cast<const int4*>(&Abuf[i * 512 + ((c ^ (i & 7)) << 4)]);
    *reinterpret_cast<int4*>(
        reinterpret_cast<uint8_t*>(Y) + (size_t)b0 * 8192 + i * 512 + c * 16) = v;
  }
}

// ---- tail: levels n=256..1 in ONE block (interleaved state, WbfI) ----
__global__ __launch_bounds__(512, 1)
void tail_kernel(const uint16_t* __restrict__ X, const uint16_t* __restrict__ WbfI,
                 const float* __restrict__ wnp, const int* __restrict__ nidx,
                 int base_off, float* __restrict__ out)
{
  __shared__ uint8_t P[98304];   // ping-pong: @0 (<=64KB) / @65536 (<=32KB)
  const int tid = threadIdx.x, wv = tid >> 6, lane = tid & 63;
  const int l15 = lane & 15, l4 = lane >> 4;
  const int col = wv * 16 + l15;

  bf16x8 bfrag[8];
  load_bfrag8(WbfI, col, l4, bfrag);

  int off = base_off;

  // n=256: 256 A-rows (interleaved, unswizzled) from global -> P0 (128 A-rows)
  for (int t = 0; t < 4; ++t) {
    f32x4 acc[4] = {};
#pragma unroll
    for (int s = 0; s < 8; ++s)
#pragma unroll
      for (int rf = 0; rf < 4; ++rf) {
        bf16x8 a = *reinterpret_cast<const bf16x8*>(
            X + (size_t)(t * 64 + rf * 16 + l15) * 256 + s * 32 + l4 * 8);
        acc[rf] = MFMA(a, bfrag[s], acc[rf], 0, 0, 0);
      }
#pragma unroll
    for (int rf = 0; rf < 4; ++rf)
#pragma unroll
      for (int p = 0; p < 2; ++p) {
        const int r1 = t * 64 + rf * 16 + l4 * 4 + 2 * p;   // [0,256)
        const int2 ni = *reinterpret_cast<const int2*>(nidx + off + r1);
        *reinterpret_cast<uint32_t*>(&P[ildw_addr(r1 >> 1, col)]) =
            pkcvt(ftanh(acc[rf][2 * p]     + wnp[ni.x * 128 + col]),
                  ftanh(acc[rf][2 * p + 1] + wnp[ni.y * 128 + col]));
      }
  }
  off += 256;
  __syncthreads();

  int cur = 0;                               // A for n=128 at P0
  for (int n = 128; n >= 1; n >>= 1) {
    const uint8_t* Pin = P + (cur ? 65536 : 0);
    uint8_t* Pout = P + (cur ? 0 : 65536);
    const int ntiles = (n + 63) >> 6;
    for (int t = 0; t < ntiles; ++t) {
      f32x4 acc[4] = {};
      gemmN<4>(Pin + t * 32768, bfrag, l15, l4, acc);
      if (n == 1) {
        if (l4 == 0) {                       // row 0 = acc[0][0] of l4==0 lanes;
          const int nix = nidx[off];         // each wave writes its own 16 cols
          out[col] = ftanh(acc[0][0] + wnp[nix * 128 + col]);
        }
      } else {
#pragma unroll
        for (int rf = 0; rf < 4; ++rf)
#pragma unroll
          for (int p = 0; p < 2; ++p) {
            const int r1 = t * 64 + rf * 16 + l4 * 4 + 2 * p;
            const int rb = (r1 < n) ? r1 : 0;            // in-range pair base
            const int2 ni = *reinterpret_cast<const int2*>(nidx + off + rb);
            const uint32_t pkv =
                pkcvt(ftanh(acc[rf][2 * p]     + wnp[ni.x * 128 + col]),
                      ftanh(acc[rf][2 * p + 1] + wnp[ni.y * 128 + col]));
            if (r1 < n)
              *reinterpret_cast<uint32_t*>(&Pout[ildw_addr(r1 >> 1, col)]) = pkv;
          }
      }
    }
    off += n;
    cur ^= 1;
    __syncthreads();
  }
}

// ---- prep: WbfN/WbfI (natural / interleaved-k Wc_w), pos/wrd bf16, wnp fp32 ----
// groups of 8: WbfN 4096, WbfI 4096, pos 512, wrd 800000, wnp 1024 = 809728.
__global__ void prep_all(const float* __restrict__ Wc_w, const float* __restrict__ Wpos,
                         const float* __restrict__ Wwrd, const float* __restrict__ Wnon,
                         const float* __restrict__ bias,
                         uint16_t* __restrict__ WbfN, uint16_t* __restrict__ WbfI,
                         uint16_t* __restrict__ pos_bf, uint16_t* __restrict__ wrd_bf,
                         float* __restrict__ wnp)
{
  int g = blockIdx.x * 256 + threadIdx.x;
  if (g < 8192) {                            // B matrices
    const bool INT = g >= 4096;
    const int gg = INT ? g - 4096 : g;
    uint16_t* dst = INT ? WbfI : WbfN;
    const int colc = gg >> 5, kg = gg & 31;
    uint16_t u[8];
#pragma unroll
    for (int i = 0; i < 8; ++i) {
      const int kk = kg * 8 + i;
      const int k = INT ? ((kk >> 1) + (kk & 1) * 128) : kk;
      u[i] = f2bf(Wc_w[colc * 256 + k]);
    }
    *reinterpret_cast<int4*>(dst + colc * 256 + kg * 8) = *reinterpret_cast<const int4*>(u);
    return;
  }
  int h = g - 8192;
  if (h < 800512) {                          // pos (512) + wrd (800000)
    const float* src; uint16_t* dst; int idx;
    if (h < 512) { src = Wpos; dst = pos_bf; idx = h; }
    else         { src = Wwrd; dst = wrd_bf; idx = h - 512; }
    float4 f0 = reinterpret_cast<const float4*>(src)[idx * 2];
    float4 f1 = reinterpret_cast<const float4*>(src)[idx * 2 + 1];
    union { int4 v; uint16_t u[8]; } pkv;
    pkv.u[0] = f2bf(f0.x); pkv.u[1] = f2bf(f0.y); pkv.u[2] = f2bf(f0.z); pkv.u[3] = f2bf(f0.w);
    pkv.u[4] = f2bf(f1.x); pkv.u[5] = f2bf(f1.y); pkv.u[6] = f2bf(f1.z); pkv.u[7] = f2bf(f1.w);
    reinterpret_cast<int4*>(dst)[idx] = pkv.v;
    return;
  }
  h -= 800512;
  if (h < 1024) {                            // wnp = Wnon + bias (fp32)
    float4 f0 = reinterpret_cast<const float4*>(Wnon)[h * 2];
    float4 f1 = reinterpret_cast<const float4*>(Wnon)[h * 2 + 1];
    const int cb = (h * 8) & 127;
    f0.x += bias[cb];     f0.y += bias[cb + 1]; f0.z += bias[cb + 2]; f0.w += bias[cb + 3];
    f1.x += bias[cb + 4]; f1.y += bias[cb + 5]; f1.z += bias[cb + 6]; f1.w += bias[cb + 7];
    reinterpret_cast<float4*>(wnp)[h * 2] = f0;
    reinterpret_cast<float4*>(wnp)[h * 2 + 1] = f1;
  }
}

extern "C" void kernel_launch(void* const* d_in, const int* in_sizes, int n_in,
                              void* d_out, int out_size, void* d_ws, size_t ws_size,
                              hipStream_t stream)
{
  const int*   pos_idx = (const int*)d_in[0];
  const int*   wrd_idx = (const int*)d_in[1];
  const int*   non_idx = (const int*)d_in[2];
  const float* Wwrd    = (const float*)d_in[3];
  const float* Wpos    = (const float*)d_in[4];
  const float* Wnon    = (const float*)d_in[5];
  const float* Wc_w    = (const float*)d_in[6];
  const float* Wc_b    = (const float*)d_in[7];
  float* out = (float*)d_out;

  uint8_t* ws = (uint8_t*)d_ws;
  uint16_t* WbfN   = (uint16_t*)ws;                    // 64 KiB
  uint16_t* WbfI   = (uint16_t*)(ws + 65536);          // 64 KiB
  uint16_t* pos_bf = (uint16_t*)(ws + 131072);         // 8 KiB
  float*    wnp    = (float*)(ws + 139264);            // 32 KiB
  uint16_t* wrd_bf = (uint16_t*)(ws + 172032);         // 12.8 MB
  uint16_t* S1     = (uint16_t*)(ws + 12972032);       // 16.8 MB (32768 A-rows)
  uint16_t* S2     = (uint16_t*)(ws + 29749248);       // 2.1 MB  (4096 A-rows)
  uint16_t* S4     = (uint16_t*)(ws + 31846400);       // 128 KB  (256 A-rows)

  prep_all<<<3163, 256, 0, stream>>>(Wc_w, Wpos, Wwrd, Wnon, Wc_b,
                                     WbfN, WbfI, pos_bf, wrd_bf, wnp);

  // Level offsets: L1=0(262144), L2=262144(131072), L3=393216(65536),
  // L4=458752(32768), L5=491520(16384), L6=507904(8192), L7=516096(4096),
  // L8=520192(2048), L9=522240(1024), L10=523264(512), tail 523776(256..1).

  // K1: gather -> L1,L2,L3 -> S1
  fused_kernel<true, false><<<2048, 512, 0, stream>>>(
      nullptr, pos_idx, wrd_idx, pos_bf, wrd_bf, S1, WbfN, WbfI, wnp, non_idx,
      0, 262144, 393216, 0);
  // K2: S1 -> L4,L5,L6 -> S2
  fused_kernel<false, false><<<256, 512, 0, stream>>>(
      S1, nullptr, nullptr, nullptr, nullptr, S2, WbfN, WbfI, wnp, non_idx,
      458752, 491520, 507904, 0);
  // K3: S2 -> L7,L8,L9,L10 -> S4
  fused_kernel<false, true><<<32, 512, 0, stream>>>(
      S2, nullptr, nullptr, nullptr, nullptr, S4, WbfN, WbfI, wnp, non_idx,
      516096, 520192, 522240, 523264);
  // tail: 256..1 (reads 256 A-rows in S4)
  tail_kernel<<<1, 512, 0, stream>>>(S4, WbfI, wnp, non_idx, 523776, out);
}

// Round 20
// 127.171 us; speedup vs baseline: 1.2662x; 1.2272x over previous
//
#include <hip/hip_runtime.h>
#include <hip/hip_bf16.h>
#include <stdint.h>

typedef __attribute__((ext_vector_type(8))) __bf16 bf16x8;
typedef __attribute__((ext_vector_type(4))) float f32x4;

#define MFMA __builtin_amdgcn_mfma_f32_16x16x32_bf16

// fp32 -> bf16 round-to-nearest-even (prep only)
__device__ __forceinline__ uint16_t f2bf(float f) {
  uint32_t u = __float_as_uint(f);
  return (uint16_t)((u + 0x7fffu + ((u >> 16) & 1u)) >> 16);
}

// paired fp32x2 -> bf16x2 via intrinsic (compiler emits v_cvt_pk_bf16_f32)
__device__ __forceinline__ uint32_t pkcvt(float lo, float hi) {
  union { __hip_bfloat162 b; uint32_t u; } cv;
  cv.b = __float22bfloat162_rn(float2{lo, hi});
  return cv.u;
}

// fast tanh, clamp-free: 1 - 2/(1+e^{2x}); IEEE-exact at +-inf; 5 VALU ops
__device__ __forceinline__ float ftanh(float v) {
  float e = __builtin_amdgcn_exp2f(v * 2.885390081777927f);
  return 1.f - 2.f * __builtin_amdgcn_rcpf(e + 1.f);
}

// async 16B global->LDS (zero staging VGPRs)
__device__ __forceinline__ void gl2lds16(const void* g, void* l) {
  __builtin_amdgcn_global_load_lds(
      (const __attribute__((address_space(1))) unsigned int*)g,
      (__attribute__((address_space(3))) unsigned int*)l, 16, 0, 0);
}

// A-tile LDS addr: row-major [rows][512B], 16B chunks XOR (row&7) (T2).
// Staging writes LINEAR; the XOR is applied to the per-lane global SOURCE.
__device__ __forceinline__ int lds_addr(int row, int chunk) {
  return row * 512 + ((chunk ^ (row & 7)) << 4);
}
// u32 store addr for interleaved pair (k'=2col, 2col+1) in A-row r2
__device__ __forceinline__ int ildw_addr(int r2, int col) {
  return r2 * 512 + (((col >> 2) ^ (r2 & 7)) << 4) + ((col & 3) << 2);
}

// 16-cols-per-wave GEMM: NRF*16 out rows x 16 cols; bfrag (32 VGPR) resident.
template<int NRF>
__device__ __forceinline__ void gemmN(const uint8_t* base, const bf16x8 bfrag[8],
                                      int l15, int l4, f32x4 acc[NRF]) {
  __builtin_amdgcn_s_setprio(1);
#pragma unroll
  for (int s = 0; s < 8; ++s) {
#pragma unroll
    for (int rf = 0; rf < NRF; ++rf) {
      bf16x8 a = *reinterpret_cast<const bf16x8*>(&base[lds_addr(rf * 16 + l15, s * 4 + l4)]);
      acc[rf] = MFMA(a, bfrag[s], acc[rf], 0, 0, 0);
    }
  }
  __builtin_amdgcn_s_setprio(0);
}

__device__ __forceinline__ void load_bfrag8(const uint16_t* __restrict__ Wb,
                                            int col, int l4, bf16x8 bfrag[8]) {
#pragma unroll
  for (int s = 0; s < 8; ++s)
    bfrag[s] = *reinterpret_cast<const bf16x8*>(Wb + col * 256 + s * 32 + l4 * 8);
}

// ---- fused 3/4-level kernel, 48 KiB LDS, INTERLEAVED state (k'=2col+side) ----
// Global state = A-format: A-row r2 holds rows [2r2, 2r2+1], unswizzled.
// Leaf L1 uses natural-order WbfN; all other levels use interleaved WbfI.
// Regions: A/Mid1 [0,32K); Mid2 [32K,48K); FOUR=false: OutS [0,8K);
//          FOUR=true:  Mid3 [0,8K), OutS4 [32K,36K).
template<bool LEAF, bool FOUR>
__global__ __launch_bounds__(512, 4)
void fused_kernel(const uint16_t* __restrict__ X,
                  const int* __restrict__ pos_idx, const int* __restrict__ wrd_idx,
                  const uint16_t* __restrict__ pos_bf, const uint16_t* __restrict__ wrd_bf,
                  uint16_t* __restrict__ Y,
                  const uint16_t* __restrict__ WbfN, const uint16_t* __restrict__ WbfI,
                  const float* __restrict__ wnp,
                  const int* __restrict__ nidx, int off1, int off2, int off3, int off4)
{
  __shared__ uint8_t Abuf[49152];
  const int tid = threadIdx.x, wv = tid >> 6, lane = tid & 63;
  const int l15 = lane & 15, l4 = lane >> 4;
  const int col = wv * 16 + l15;
  const int b0 = blockIdx.x;

  bf16x8 bfrag[8];
  load_bfrag8(LEAF ? WbfN : WbfI, col, l4, bfrag);

  uint32_t pk1[2][8];

  // ---- L1: two 64-row tiles through Abuf[0:32K) ----
#pragma unroll
  for (int t = 0; t < 2; ++t) {
#pragma unroll
    for (int k = 0; k < 4; ++k) {
      const int ct = tid + k * 512;          // linear LDS chunk [0,2048)
      const int arow = ct >> 5;
      const int c = (ct & 31) ^ (arow & 7);  // pre-swizzled logical chunk
      const void* src;
      if (LEAF) {
        const int seg = c >> 3;              // [posL|wrdL|posR|wrdR]
        const int leaf = 2 * (b0 * 128 + t * 64 + arow) + (seg >> 1);
        const int idx = (seg & 1) ? wrd_idx[leaf] : pos_idx[leaf];
        const uint16_t* tab = (seg & 1) ? wrd_bf : pos_bf;
        src = tab + (size_t)idx * 64 + (c & 7) * 8;
      } else {
        src = X + ((size_t)(b0 * 128 + t * 64 + arow)) * 256 + c * 8;
      }
      gl2lds16(src, &Abuf[ct << 4]);
    }
    __syncthreads();                         // staged

    f32x4 acc[4] = {};
    gemmN<4>(Abuf, bfrag, l15, l4, acc);
#pragma unroll
    for (int rf = 0; rf < 4; ++rf)
#pragma unroll
      for (int p = 0; p < 2; ++p) {
        const int r1 = t * 64 + rf * 16 + l4 * 4 + 2 * p;
        const int2 ni = *reinterpret_cast<const int2*>(nidx + off1 + b0 * 128 + r1);
        pk1[t][rf * 2 + p] = pkcvt(ftanh(acc[rf][2 * p]     + wnp[ni.x * 128 + col]),
                                   ftanh(acc[rf][2 * p + 1] + wnp[ni.y * 128 + col]));
      }
    __syncthreads();                         // tile t LDS reads done
  }

  if (LEAF) load_bfrag8(WbfI, col, l4, bfrag);   // interleaved B for L2+

  // ---- Mid1 write: 16 u32 pair-stores -> [0,32K) ----
#pragma unroll
  for (int t = 0; t < 2; ++t)
#pragma unroll
    for (int rf = 0; rf < 4; ++rf)
#pragma unroll
      for (int p = 0; p < 2; ++p) {
        const int r2 = t * 32 + rf * 8 + l4 * 2 + p;
        *reinterpret_cast<uint32_t*>(&Abuf[ildw_addr(r2, col)]) = pk1[t][rf * 2 + p];
      }
  __syncthreads();                           // Mid1 complete

  // ---- L2: gemm from Mid1; pair epilogue -> Mid2 [32K,48K) direct ----
  {
    f32x4 acc[4] = {};
    gemmN<4>(Abuf, bfrag, l15, l4, acc);
    uint8_t* Mid2 = Abuf + 32768;
#pragma unroll
    for (int rf = 0; rf < 4; ++rf)
#pragma unroll
      for (int p = 0; p < 2; ++p) {
        const int r2 = rf * 16 + l4 * 4 + 2 * p;        // L2 row [0,64)
        const int2 ni = *reinterpret_cast<const int2*>(nidx + off2 + b0 * 64 + r2);
        *reinterpret_cast<uint32_t*>(&Mid2[ildw_addr(r2 >> 1, col)]) =
            pkcvt(ftanh(acc[rf][2 * p]     + wnp[ni.x * 128 + col]),
                  ftanh(acc[rf][2 * p + 1] + wnp[ni.y * 128 + col]));
      }
  }
  __syncthreads();                           // Mid2 complete (+ Mid1 reads done)

  // ---- L3: gemm from Mid2 (32 rows); pair epilogue -> [0,8K) direct ----
  {
    f32x4 acc[2] = {};
    gemmN<2>(Abuf + 32768, bfrag, l15, l4, acc);
#pragma unroll
    for (int rf = 0; rf < 2; ++rf)
#pragma unroll
      for (int p = 0; p < 2; ++p) {
        const int r3 = rf * 16 + l4 * 4 + 2 * p;        // L3 row [0,32)
        const int2 ni = *reinterpret_cast<const int2*>(nidx + off3 + b0 * 32 + r3);
        *reinterpret_cast<uint32_t*>(&Abuf[ildw_addr(r3 >> 1, col)]) =
            pkcvt(ftanh(acc[rf][2 * p]     + wnp[ni.x * 128 + col]),
                  ftanh(acc[rf][2 * p + 1] + wnp[ni.y * 128 + col]));
      }
  }
  __syncthreads();                           // L3out complete (+ Mid2 reads done)

  if (FOUR) {
    // ---- L4: gemm from [0,8K) (16 A-rows); pair epilogue -> [32K,36K) ----
    f32x4 acc[1] = {};
    gemmN<1>(Abuf, bfrag, l15, l4, acc);
    uint8_t* O4 = Abuf + 32768;
#pragma unroll
    for (int p = 0; p < 2; ++p) {
      const int r4 = l4 * 4 + 2 * p;                    // L4 row [0,16)
      const int2 ni = *reinterpret_cast<const int2*>(nidx + off4 + b0 * 16 + r4);
      *reinterpret_cast<uint32_t*>(&O4[ildw_addr(r4 >> 1, col)]) =
          pkcvt(ftanh(acc[0][2 * p]     + wnp[ni.x * 128 + col]),
                ftanh(acc[0][2 * p + 1] + wnp[ni.y * 128 + col]));
    }
    __syncthreads();
    if (tid < 256) {                         // 8 A-rows x 512B = 4KB out (de-swizzle)
      const int i = tid >> 5, c = tid & 31;
      int4 v = *reinterpret_cast<const int4*>(&O4[i * 512 + ((c ^ (i & 7)) << 4)]);
      *reinterpret_cast<int4*>(
          reinterpret_cast<uint8_t*>(Y) + (size_t)b0 * 4096 + i * 512 + c * 16) = v;
    }
  } else {
    const int i = tid >> 5, c = tid & 31;    // 16 A-rows x 512B = 8KB out (de-swizzle)
    int4 v = *reinterpret_cast<const int4*>(&Abuf[i * 512 + ((c ^ (i & 7)) << 4)]);
    *reinterpret_cast<int4*>(
        reinterpret_cast<uint8_t*>(Y) + (size_t)b0 * 8192 + i * 512 + c * 16) = v;
  }
}

// ---- tail: levels n=128..1 in ONE block (interleaved state, WbfI) ----
__global__ __launch_bounds__(512, 1)
void tail_kernel(const uint16_t* __restrict__ X, const uint16_t* __restrict__ WbfI,
                 const float* __restrict__ wnp, const int* __restrict__ nidx,
                 int base_off, float* __restrict__ out)
{
  __shared__ uint8_t P[98304];   // ping-pong: @0 (<=32KB) / @65536 (<=16KB)
  const int tid = threadIdx.x, wv = tid >> 6, lane = tid & 63;
  const int l15 = lane & 15, l4 = lane >> 4;
  const int col = wv * 16 + l15;

  bf16x8 bfrag[8];
  load_bfrag8(WbfI, col, l4, bfrag);

  int off = base_off;                        // n=128 level

  // n=128: 128 A-rows (interleaved, unswizzled) from global -> P0 (64 A-rows)
  for (int t = 0; t < 2; ++t) {
    f32x4 acc[4] = {};
#pragma unroll
    for (int s = 0; s < 8; ++s)
#pragma unroll
      for (int rf = 0; rf < 4; ++rf) {
        bf16x8 a = *reinterpret_cast<const bf16x8*>(
            X + (size_t)(t * 64 + rf * 16 + l15) * 256 + s * 32 + l4 * 8);
        acc[rf] = MFMA(a, bfrag[s], acc[rf], 0, 0, 0);
      }
#pragma unroll
    for (int rf = 0; rf < 4; ++rf)
#pragma unroll
      for (int p = 0; p < 2; ++p) {
        const int r1 = t * 64 + rf * 16 + l4 * 4 + 2 * p;   // [0,128)
        const int2 ni = *reinterpret_cast<const int2*>(nidx + off + r1);
        *reinterpret_cast<uint32_t*>(&P[ildw_addr(r1 >> 1, col)]) =
            pkcvt(ftanh(acc[rf][2 * p]     + wnp[ni.x * 128 + col]),
                  ftanh(acc[rf][2 * p + 1] + wnp[ni.y * 128 + col]));
      }
  }
  off += 128;
  __syncthreads();

  int cur = 0;                               // A for n=64 at P0
  for (int n = 64; n >= 1; n >>= 1) {
    const uint8_t* Pin = P + (cur ? 65536 : 0);
    uint8_t* Pout = P + (cur ? 0 : 65536);
    f32x4 acc[4] = {};
    gemmN<4>(Pin, bfrag, l15, l4, acc);      // reads A-rows 0..63 (garbage > n ok)
    if (n == 1) {
      if (l4 == 0) {                         // row 0 = acc[0][0] of l4==0 lanes;
        const int nix = nidx[off];           // each wave writes its own 16 cols
        out[col] = ftanh(acc[0][0] + wnp[nix * 128 + col]);
      }
    } else {
#pragma unroll
      for (int rf = 0; rf < 4; ++rf)
#pragma unroll
        for (int p = 0; p < 2; ++p) {
          const int r1 = rf * 16 + l4 * 4 + 2 * p;
          const int rb = (r1 < n) ? r1 : 0;              // in-range pair base
          const int2 ni = *reinterpret_cast<const int2*>(nidx + off + rb);
          const uint32_t pkv =
              pkcvt(ftanh(acc[rf][2 * p]     + wnp[ni.x * 128 + col]),
                    ftanh(acc[rf][2 * p + 1] + wnp[ni.y * 128 + col]));
          if (r1 < n)
            *reinterpret_cast<uint32_t*>(&Pout[ildw_addr(r1 >> 1, col)]) = pkv;
        }
    }
    off += n;
    cur ^= 1;
    __syncthreads();
  }
}

// ---- prep: WbfN/WbfI (natural / interleaved-k Wc_w), pos/wrd bf16, wnp fp32 ----
// groups of 8: WbfN 4096, WbfI 4096, pos 512, wrd 800000, wnp 1024 = 809728.
__global__ void prep_all(const float* __restrict__ Wc_w, const float* __restrict__ Wpos,
                         const float* __restrict__ Wwrd, const float* __restrict__ Wnon,
                         const float* __restrict__ bias,
                         uint16_t* __restrict__ WbfN, uint16_t* __restrict__ WbfI,
                         uint16_t* __restrict__ pos_bf, uint16_t* __restrict__ wrd_bf,
                         float* __restrict__ wnp)
{
  int g = blockIdx.x * 256 + threadIdx.x;
  if (g < 8192) {                            // B matrices
    const bool INT = g >= 4096;
    const int gg = INT ? g - 4096 : g;
    uint16_t* dst = INT ? WbfI : WbfN;
    const int colc = gg >> 5, kg = gg & 31;
    uint16_t u[8];
#pragma unroll
    for (int i = 0; i < 8; ++i) {
      const int kk = kg * 8 + i;
      const int k = INT ? ((kk >> 1) + (kk & 1) * 128) : kk;
      u[i] = f2bf(Wc_w[colc * 256 + k]);
    }
    *reinterpret_cast<int4*>(dst + colc * 256 + kg * 8) = *reinterpret_cast<const int4*>(u);
    return;
  }
  int h = g - 8192;
  if (h < 800512) {                          // pos (512) + wrd (800000)
    const float* src; uint16_t* dst; int idx;
    if (h < 512) { src = Wpos; dst = pos_bf; idx = h; }
    else         { src = Wwrd; dst = wrd_bf; idx = h - 512; }
    float4 f0 = reinterpret_cast<const float4*>(src)[idx * 2];
    float4 f1 = reinterpret_cast<const float4*>(src)[idx * 2 + 1];
    union { int4 v; uint16_t u[8]; } pkv;
    pkv.u[0] = f2bf(f0.x); pkv.u[1] = f2bf(f0.y); pkv.u[2] = f2bf(f0.z); pkv.u[3] = f2bf(f0.w);
    pkv.u[4] = f2bf(f1.x); pkv.u[5] = f2bf(f1.y); pkv.u[6] = f2bf(f1.z); pkv.u[7] = f2bf(f1.w);
    reinterpret_cast<int4*>(dst)[idx] = pkv.v;
    return;
  }
  h -= 800512;
  if (h < 1024) {                            // wnp = Wnon + bias (fp32)
    float4 f0 = reinterpret_cast<const float4*>(Wnon)[h * 2];
    float4 f1 = reinterpret_cast<const float4*>(Wnon)[h * 2 + 1];
    const int cb = (h * 8) & 127;
    f0.x += bias[cb];     f0.y += bias[cb + 1]; f0.z += bias[cb + 2]; f0.w += bias[cb + 3];
    f1.x += bias[cb + 4]; f1.y += bias[cb + 5]; f1.z += bias[cb + 6]; f1.w += bias[cb + 7];
    reinterpret_cast<float4*>(wnp)[h * 2] = f0;
    reinterpret_cast<float4*>(wnp)[h * 2 + 1] = f1;
  }
}

extern "C" void kernel_launch(void* const* d_in, const int* in_sizes, int n_in,
                              void* d_out, int out_size, void* d_ws, size_t ws_size,
                              hipStream_t stream)
{
  const int*   pos_idx = (const int*)d_in[0];
  const int*   wrd_idx = (const int*)d_in[1];
  const int*   non_idx = (const int*)d_in[2];
  const float* Wwrd    = (const float*)d_in[3];
  const float* Wpos    = (const float*)d_in[4];
  const float* Wnon    = (const float*)d_in[5];
  const float* Wc_w    = (const float*)d_in[6];
  const float* Wc_b    = (const float*)d_in[7];
  float* out = (float*)d_out;

  uint8_t* ws = (uint8_t*)d_ws;
  uint16_t* WbfN   = (uint16_t*)ws;                    // 64 KiB
  uint16_t* WbfI   = (uint16_t*)(ws + 65536);          // 64 KiB
  uint16_t* pos_bf = (uint16_t*)(ws + 131072);         // 8 KiB
  float*    wnp    = (float*)(ws + 139264);            // 32 KiB
  uint16_t* wrd_bf = (uint16_t*)(ws + 172032);         // 12.8 MB
  uint16_t* S1     = (uint16_t*)(ws + 12972032);       // 16.8 MB (32768 A-rows)
  uint16_t* S2     = (uint16_t*)(ws + 29749248);       // 1 MB   (2048 A-rows)
  uint16_t* S4     = (uint16_t*)(ws + 31846400);       // 64 KB  (128 A-rows)

  prep_all<<<3163, 256, 0, stream>>>(Wc_w, Wpos, Wwrd, Wnon, Wc_b,
                                     WbfN, WbfI, pos_bf, wrd_bf, wnp);

  // Level offsets: L1=0(262144), L2=262144(131072), L3=393216(65536),
  // L4=458752(32768), L5=491520(16384), L6=507904(8192), L7=516096(4096),
  // L8=520192(2048), L9=522240(1024), L10=523264(512), n256=523776,
  // n128=524032, then 524160(64)... tail.

  // K1: gather -> L1,L2,L3 -> S1 (32768 A-rows)
  fused_kernel<true, false><<<2048, 512, 0, stream>>>(
      nullptr, pos_idx, wrd_idx, pos_bf, wrd_bf, S1, WbfN, WbfI, wnp, non_idx,
      0, 262144, 393216, 0);
  // K2: S1 -> L4,L5,L6,L7 -> S2 (2048 A-rows = n=4096)
  fused_kernel<false, true><<<256, 512, 0, stream>>>(
      S1, nullptr, nullptr, nullptr, nullptr, S2, WbfN, WbfI, wnp, non_idx,
      458752, 491520, 507904, 516096);
  // K3: S2 -> L8,L9,L10,n256 -> S4 (128 A-rows = n=256)
  fused_kernel<false, true><<<16, 512, 0, stream>>>(
      S2, nullptr, nullptr, nullptr, nullptr, S4, WbfN, WbfI, wnp, non_idx,
      520192, 522240, 523264, 523776);
  // tail: 128..1 (reads 128 A-rows in S4)
  tail_kernel<<<1, 512, 0, stream>>>(S4, WbfI, wnp, non_idx, 524032, out);
}

// Round 21
// 121.812 us; speedup vs baseline: 1.3219x; 1.0440x over previous
//
#include <hip/hip_runtime.h>
#include <hip/hip_bf16.h>
#include <stdint.h>

typedef __attribute__((ext_vector_type(8))) __bf16 bf16x8;
typedef __attribute__((ext_vector_type(4))) float f32x4;

#define MFMA __builtin_amdgcn_mfma_f32_16x16x32_bf16

// fp32 -> bf16 round-to-nearest-even (prep only)
__device__ __forceinline__ uint16_t f2bf(float f) {
  uint32_t u = __float_as_uint(f);
  return (uint16_t)((u + 0x7fffu + ((u >> 16) & 1u)) >> 16);
}

// paired fp32x2 -> bf16x2 via intrinsic (compiler emits v_cvt_pk_bf16_f32)
__device__ __forceinline__ uint32_t pkcvt(float lo, float hi) {
  union { __hip_bfloat162 b; uint32_t u; } cv;
  cv.b = __float22bfloat162_rn(float2{lo, hi});
  return cv.u;
}

// fast tanh, clamp-free: 1 - 2/(1+e^{2x}); IEEE-exact at +-inf; 5 VALU ops
__device__ __forceinline__ float ftanh(float v) {
  float e = __builtin_amdgcn_exp2f(v * 2.885390081777927f);
  return 1.f - 2.f * __builtin_amdgcn_rcpf(e + 1.f);
}

// async 16B global->LDS (zero staging VGPRs)
__device__ __forceinline__ void gl2lds16(const void* g, void* l) {
  __builtin_amdgcn_global_load_lds(
      (const __attribute__((address_space(1))) unsigned int*)g,
      (__attribute__((address_space(3))) unsigned int*)l, 16, 0, 0);
}

// A-tile LDS addr: row-major [rows][512B], 16B chunks XOR (row&7) (T2).
// Staging writes LINEAR; the XOR is applied to the per-lane global SOURCE.
__device__ __forceinline__ int lds_addr(int row, int chunk) {
  return row * 512 + ((chunk ^ (row & 7)) << 4);
}
// u32 store addr for interleaved pair (k'=2col, 2col+1) in A-row r2
__device__ __forceinline__ int ildw_addr(int r2, int col) {
  return r2 * 512 + (((col >> 2) ^ (r2 & 7)) << 4) + ((col & 3) << 2);
}

// 16-cols-per-wave GEMM: NRF*16 out rows x 16 cols; bfrag (32 VGPR) resident.
template<int NRF>
__device__ __forceinline__ void gemmN(const uint8_t* base, const bf16x8 bfrag[8],
                                      int l15, int l4, f32x4 acc[NRF]) {
  __builtin_amdgcn_s_setprio(1);
#pragma unroll
  for (int s = 0; s < 8; ++s) {
#pragma unroll
    for (int rf = 0; rf < NRF; ++rf) {
      bf16x8 a = *reinterpret_cast<const bf16x8*>(&base[lds_addr(rf * 16 + l15, s * 4 + l4)]);
      acc[rf] = MFMA(a, bfrag[s], acc[rf], 0, 0, 0);
    }
  }
  __builtin_amdgcn_s_setprio(0);
}

__device__ __forceinline__ void load_bfrag8(const uint16_t* __restrict__ Wb,
                                            int col, int l4, bf16x8 bfrag[8]) {
#pragma unroll
  for (int s = 0; s < 8; ++s)
    bfrag[s] = *reinterpret_cast<const bf16x8*>(Wb + col * 256 + s * 32 + l4 * 8);
}

// ---- fused 3/4-level kernel, 48 KiB LDS, INTERLEAVED state (k'=2col+side) ----
// Global state = A-format: A-row r2 holds rows [2r2, 2r2+1], unswizzled.
// Leaf L1 uses natural-order WbfN; all other levels use interleaved WbfI.
// Regions: A/Mid1 [0,32K); Mid2 [32K,48K); FOUR=false: OutS [0,8K);
//          FOUR=true:  Mid3 [0,8K), OutS4 [32K,36K).
template<bool LEAF, bool FOUR>
__global__ __launch_bounds__(512, 4)
void fused_kernel(const uint16_t* __restrict__ X,
                  const int* __restrict__ pos_idx, const int* __restrict__ wrd_idx,
                  const uint16_t* __restrict__ pos_bf, const uint16_t* __restrict__ wrd_bf,
                  uint16_t* __restrict__ Y,
                  const uint16_t* __restrict__ WbfN, const uint16_t* __restrict__ WbfI,
                  const float* __restrict__ wnp,
                  const int* __restrict__ nidx, int off1, int off2, int off3, int off4)
{
  __shared__ uint8_t Abuf[49152];
  const int tid = threadIdx.x, wv = tid >> 6, lane = tid & 63;
  const int l15 = lane & 15, l4 = lane >> 4;
  const int col = wv * 16 + l15;
  const int b0 = blockIdx.x;

  bf16x8 bfrag[8];
  load_bfrag8(LEAF ? WbfN : WbfI, col, l4, bfrag);

  uint32_t pk1[2][8];

  // ---- L1: two 64-row tiles through Abuf[0:32K) ----
#pragma unroll
  for (int t = 0; t < 2; ++t) {
#pragma unroll
    for (int k = 0; k < 4; ++k) {
      const int ct = tid + k * 512;          // linear LDS chunk [0,2048)
      const int arow = ct >> 5;
      const int c = (ct & 31) ^ (arow & 7);  // pre-swizzled logical chunk
      const void* src;
      if (LEAF) {
        const int seg = c >> 3;              // [posL|wrdL|posR|wrdR]
        const int leaf = 2 * (b0 * 128 + t * 64 + arow) + (seg >> 1);
        const int idx = (seg & 1) ? wrd_idx[leaf] : pos_idx[leaf];
        const uint16_t* tab = (seg & 1) ? wrd_bf : pos_bf;
        src = tab + (size_t)idx * 64 + (c & 7) * 8;
      } else {
        src = X + ((size_t)(b0 * 128 + t * 64 + arow)) * 256 + c * 8;
      }
      gl2lds16(src, &Abuf[ct << 4]);
    }
    __syncthreads();                         // staged

    f32x4 acc[4] = {};
    gemmN<4>(Abuf, bfrag, l15, l4, acc);
#pragma unroll
    for (int rf = 0; rf < 4; ++rf)
#pragma unroll
      for (int p = 0; p < 2; ++p) {
        const int r1 = t * 64 + rf * 16 + l4 * 4 + 2 * p;
        const int2 ni = *reinterpret_cast<const int2*>(nidx + off1 + b0 * 128 + r1);
        pk1[t][rf * 2 + p] = pkcvt(ftanh(acc[rf][2 * p]     + wnp[ni.x * 128 + col]),
                                   ftanh(acc[rf][2 * p + 1] + wnp[ni.y * 128 + col]));
      }
    __syncthreads();                         // tile t LDS reads done
  }

  if (LEAF) load_bfrag8(WbfI, col, l4, bfrag);   // interleaved B for L2+

  // ---- Mid1 write: 16 u32 pair-stores -> [0,32K) ----
#pragma unroll
  for (int t = 0; t < 2; ++t)
#pragma unroll
    for (int rf = 0; rf < 4; ++rf)
#pragma unroll
      for (int p = 0; p < 2; ++p) {
        const int r2 = t * 32 + rf * 8 + l4 * 2 + p;
        *reinterpret_cast<uint32_t*>(&Abuf[ildw_addr(r2, col)]) = pk1[t][rf * 2 + p];
      }
  __syncthreads();                           // Mid1 complete

  // ---- L2: gemm from Mid1; pair epilogue -> Mid2 [32K,48K) direct ----
  {
    f32x4 acc[4] = {};
    gemmN<4>(Abuf, bfrag, l15, l4, acc);
    uint8_t* Mid2 = Abuf + 32768;
#pragma unroll
    for (int rf = 0; rf < 4; ++rf)
#pragma unroll
      for (int p = 0; p < 2; ++p) {
        const int r2 = rf * 16 + l4 * 4 + 2 * p;        // L2 row [0,64)
        const int2 ni = *reinterpret_cast<const int2*>(nidx + off2 + b0 * 64 + r2);
        *reinterpret_cast<uint32_t*>(&Mid2[ildw_addr(r2 >> 1, col)]) =
            pkcvt(ftanh(acc[rf][2 * p]     + wnp[ni.x * 128 + col]),
                  ftanh(acc[rf][2 * p + 1] + wnp[ni.y * 128 + col]));
      }
  }
  __syncthreads();                           // Mid2 complete (+ Mid1 reads done)

  // ---- L3: gemm from Mid2 (32 rows); pair epilogue -> [0,8K) direct ----
  {
    f32x4 acc[2] = {};
    gemmN<2>(Abuf + 32768, bfrag, l15, l4, acc);
#pragma unroll
    for (int rf = 0; rf < 2; ++rf)
#pragma unroll
      for (int p = 0; p < 2; ++p) {
        const int r3 = rf * 16 + l4 * 4 + 2 * p;        // L3 row [0,32)
        const int2 ni = *reinterpret_cast<const int2*>(nidx + off3 + b0 * 32 + r3);
        *reinterpret_cast<uint32_t*>(&Abuf[ildw_addr(r3 >> 1, col)]) =
            pkcvt(ftanh(acc[rf][2 * p]     + wnp[ni.x * 128 + col]),
                  ftanh(acc[rf][2 * p + 1] + wnp[ni.y * 128 + col]));
      }
  }
  __syncthreads();                           // L3out complete (+ Mid2 reads done)

  if (FOUR) {
    // ---- L4: gemm from [0,8K) (16 A-rows); pair epilogue -> [32K,36K) ----
    f32x4 acc[1] = {};
    gemmN<1>(Abuf, bfrag, l15, l4, acc);
    uint8_t* O4 = Abuf + 32768;
#pragma unroll
    for (int p = 0; p < 2; ++p) {
      const int r4 = l4 * 4 + 2 * p;                    // L4 row [0,16)
      const int2 ni = *reinterpret_cast<const int2*>(nidx + off4 + b0 * 16 + r4);
      *reinterpret_cast<uint32_t*>(&O4[ildw_addr(r4 >> 1, col)]) =
          pkcvt(ftanh(acc[0][2 * p]     + wnp[ni.x * 128 + col]),
                ftanh(acc[0][2 * p + 1] + wnp[ni.y * 128 + col]));
    }
    __syncthreads();
    if (tid < 256) {                         // 8 A-rows x 512B = 4KB out (de-swizzle)
      const int i = tid >> 5, c = tid & 31;
      int4 v = *reinterpret_cast<const int4*>(&O4[i * 512 + ((c ^ (i & 7)) << 4)]);
      *reinterpret_cast<int4*>(
          reinterpret_cast<uint8_t*>(Y) + (size_t)b0 * 4096 + i * 512 + c * 16) = v;
    }
  } else {
    const int i = tid >> 5, c = tid & 31;    // 16 A-rows x 512B = 8KB out (de-swizzle)
    int4 v = *reinterpret_cast<const int4*>(&Abuf[i * 512 + ((c ^ (i & 7)) << 4)]);
    *reinterpret_cast<int4*>(
        reinterpret_cast<uint8_t*>(Y) + (size_t)b0 * 8192 + i * 512 + c * 16) = v;
  }
}

// ---- tail: levels n=64..1 in ONE block (interleaved state, WbfI) ----
// X = n128 output: 64 A-rows. First phase computes n=64 direct from global.
__global__ __launch_bounds__(512, 1)
void tail_kernel(const uint16_t* __restrict__ X, const uint16_t* __restrict__ WbfI,
                 const float* __restrict__ wnp, const int* __restrict__ nidx,
                 int base_off, float* __restrict__ out)
{
  __shared__ uint8_t P[98304];   // ping-pong: @0 (<=16KB) / @65536 (<=8KB)
  const int tid = threadIdx.x, wv = tid >> 6, lane = tid & 63;
  const int l15 = lane & 15, l4 = lane >> 4;
  const int col = wv * 16 + l15;

  bf16x8 bfrag[8];
  load_bfrag8(WbfI, col, l4, bfrag);

  int off = base_off;                        // n=64 level

  // n=64: 64 A-rows (interleaved, unswizzled) from global -> P0 (32 A-rows)
  {
    f32x4 acc[4] = {};
#pragma unroll
    for (int s = 0; s < 8; ++s)
#pragma unroll
      for (int rf = 0; rf < 4; ++rf) {
        bf16x8 a = *reinterpret_cast<const bf16x8*>(
            X + (size_t)(rf * 16 + l15) * 256 + s * 32 + l4 * 8);
        acc[rf] = MFMA(a, bfrag[s], acc[rf], 0, 0, 0);
      }
#pragma unroll
    for (int rf = 0; rf < 4; ++rf)
#pragma unroll
      for (int p = 0; p < 2; ++p) {
        const int r1 = rf * 16 + l4 * 4 + 2 * p;            // [0,64)
        const int2 ni = *reinterpret_cast<const int2*>(nidx + off + r1);
        *reinterpret_cast<uint32_t*>(&P[ildw_addr(r1 >> 1, col)]) =
            pkcvt(ftanh(acc[rf][2 * p]     + wnp[ni.x * 128 + col]),
                  ftanh(acc[rf][2 * p + 1] + wnp[ni.y * 128 + col]));
      }
  }
  off += 64;
  __syncthreads();

  int cur = 0;                               // A for n=32 at P0
  for (int n = 32; n >= 1; n >>= 1) {
    const uint8_t* Pin = P + (cur ? 65536 : 0);
    uint8_t* Pout = P + (cur ? 0 : 65536);
    f32x4 acc[4] = {};
    gemmN<4>(Pin, bfrag, l15, l4, acc);      // garbage A-rows >= n are discarded
    if (n == 1) {
      if (l4 == 0) {                         // row 0 = acc[0][0] of l4==0 lanes;
        const int nix = nidx[off];           // each wave writes its own 16 cols
        out[col] = ftanh(acc[0][0] + wnp[nix * 128 + col]);
      }
    } else {
#pragma unroll
      for (int rf = 0; rf < 4; ++rf)
#pragma unroll
        for (int p = 0; p < 2; ++p) {
          const int r1 = rf * 16 + l4 * 4 + 2 * p;
          const int rb = (r1 < n) ? r1 : 0;              // in-range pair base
          const int2 ni = *reinterpret_cast<const int2*>(nidx + off + rb);
          const uint32_t pkv =
              pkcvt(ftanh(acc[rf][2 * p]     + wnp[ni.x * 128 + col]),
                    ftanh(acc[rf][2 * p + 1] + wnp[ni.y * 128 + col]));
          if (r1 < n)
            *reinterpret_cast<uint32_t*>(&Pout[ildw_addr(r1 >> 1, col)]) = pkv;
        }
    }
    off += n;
    cur ^= 1;
    __syncthreads();
  }
}

// ---- prep: WbfN/WbfI (natural / interleaved-k Wc_w), pos/wrd bf16, wnp fp32 ----
// groups of 8: WbfN 4096, WbfI 4096, pos 512, wrd 800000, wnp 1024 = 809728.
__global__ void prep_all(const float* __restrict__ Wc_w, const float* __restrict__ Wpos,
                         const float* __restrict__ Wwrd, const float* __restrict__ Wnon,
                         const float* __restrict__ bias,
                         uint16_t* __restrict__ WbfN, uint16_t* __restrict__ WbfI,
                         uint16_t* __restrict__ pos_bf, uint16_t* __restrict__ wrd_bf,
                         float* __restrict__ wnp)
{
  int g = blockIdx.x * 256 + threadIdx.x;
  if (g < 8192) {                            // B matrices
    const bool INT = g >= 4096;
    const int gg = INT ? g - 4096 : g;
    uint16_t* dst = INT ? WbfI : WbfN;
    const int colc = gg >> 5, kg = gg & 31;
    uint16_t u[8];
#pragma unroll
    for (int i = 0; i < 8; ++i) {
      const int kk = kg * 8 + i;
      const int k = INT ? ((kk >> 1) + (kk & 1) * 128) : kk;
      u[i] = f2bf(Wc_w[colc * 256 + k]);
    }
    *reinterpret_cast<int4*>(dst + colc * 256 + kg * 8) = *reinterpret_cast<const int4*>(u);
    return;
  }
  int h = g - 8192;
  if (h < 800512) {                          // pos (512) + wrd (800000)
    const float* src; uint16_t* dst; int idx;
    if (h < 512) { src = Wpos; dst = pos_bf; idx = h; }
    else         { src = Wwrd; dst = wrd_bf; idx = h - 512; }
    float4 f0 = reinterpret_cast<const float4*>(src)[idx * 2];
    float4 f1 = reinterpret_cast<const float4*>(src)[idx * 2 + 1];
    union { int4 v; uint16_t u[8]; } pkv;
    pkv.u[0] = f2bf(f0.x); pkv.u[1] = f2bf(f0.y); pkv.u[2] = f2bf(f0.z); pkv.u[3] = f2bf(f0.w);
    pkv.u[4] = f2bf(f1.x); pkv.u[5] = f2bf(f1.y); pkv.u[6] = f2bf(f1.z); pkv.u[7] = f2bf(f1.w);
    reinterpret_cast<int4*>(dst)[idx] = pkv.v;
    return;
  }
  h -= 800512;
  if (h < 1024) {                            // wnp = Wnon + bias (fp32)
    float4 f0 = reinterpret_cast<const float4*>(Wnon)[h * 2];
    float4 f1 = reinterpret_cast<const float4*>(Wnon)[h * 2 + 1];
    const int cb = (h * 8) & 127;
    f0.x += bias[cb];     f0.y += bias[cb + 1]; f0.z += bias[cb + 2]; f0.w += bias[cb + 3];
    f1.x += bias[cb + 4]; f1.y += bias[cb + 5]; f1.z += bias[cb + 6]; f1.w += bias[cb + 7];
    reinterpret_cast<float4*>(wnp)[h * 2] = f0;
    reinterpret_cast<float4*>(wnp)[h * 2 + 1] = f1;
  }
}

extern "C" void kernel_launch(void* const* d_in, const int* in_sizes, int n_in,
                              void* d_out, int out_size, void* d_ws, size_t ws_size,
                              hipStream_t stream)
{
  const int*   pos_idx = (const int*)d_in[0];
  const int*   wrd_idx = (const int*)d_in[1];
  const int*   non_idx = (const int*)d_in[2];
  const float* Wwrd    = (const float*)d_in[3];
  const float* Wpos    = (const float*)d_in[4];
  const float* Wnon    = (const float*)d_in[5];
  const float* Wc_w    = (const float*)d_in[6];
  const float* Wc_b    = (const float*)d_in[7];
  float* out = (float*)d_out;

  uint8_t* ws = (uint8_t*)d_ws;
  uint16_t* WbfN   = (uint16_t*)ws;                    // 64 KiB
  uint16_t* WbfI   = (uint16_t*)(ws + 65536);          // 64 KiB
  uint16_t* pos_bf = (uint16_t*)(ws + 131072);         // 8 KiB
  float*    wnp    = (float*)(ws + 139264);            // 32 KiB
  uint16_t* wrd_bf = (uint16_t*)(ws + 172032);         // 12.8 MB
  uint16_t* S1     = (uint16_t*)(ws + 12972032);       // 8.4 MB (16384 A-rows, L4)
  uint16_t* S2     = (uint16_t*)(ws + 21360640);       // 0.5 MB (1024 A-rows, L8)
  uint16_t* S4     = (uint16_t*)(ws + 21885952);       // 32 KB  (64 A-rows, n128)

  prep_all<<<3163, 256, 0, stream>>>(Wc_w, Wpos, Wwrd, Wnon, Wc_b,
                                     WbfN, WbfI, pos_bf, wrd_bf, wnp);

  // Level offsets: L1=0(262144), L2=262144(131072), L3=393216(65536),
  // L4=458752(32768), L5=491520(16384), L6=507904(8192), L7=516096(4096),
  // L8=520192(2048), L9=522240(1024), L10=523264(512), n256=523776,
  // n128=524032, n64=524160, ... n1=524286.

  // K1: gather -> L1,L2,L3,L4 -> S1 (16384 A-rows)
  fused_kernel<true, true><<<2048, 512, 0, stream>>>(
      nullptr, pos_idx, wrd_idx, pos_bf, wrd_bf, S1, WbfN, WbfI, wnp, non_idx,
      0, 262144, 393216, 458752);
  // K2: S1 -> L5,L6,L7,L8 -> S2 (1024 A-rows)
  fused_kernel<false, true><<<128, 512, 0, stream>>>(
      S1, nullptr, nullptr, nullptr, nullptr, S2, WbfN, WbfI, wnp, non_idx,
      491520, 507904, 516096, 520192);
  // K3: S2 -> L9,L10,n256,n128 -> S4 (64 A-rows)
  fused_kernel<false, true><<<8, 512, 0, stream>>>(
      S2, nullptr, nullptr, nullptr, nullptr, S4, WbfN, WbfI, wnp, non_idx,
      522240, 523264, 523776, 524032);
  // tail: 64..1 (reads 64 A-rows in S4)
  tail_kernel<<<1, 512, 0, stream>>>(S4, WbfI, wnp, non_idx, 524160, out);
}